// Round 6
// baseline (726.631 us; speedup 1.0000x reference)
//
#include <hip/hip_runtime.h>
#include <math.h>

// ---- problem constants (fixed shapes) ----
#define NPTS 16384
#define DIM  512
#define KSEL 11                   // K+1 smallest incl. self; min dropped at the end
#define NSPLIT 4
#define CPS   (NPTS / NSPLIT)     // 4096 columns per split
#define BM    256                 // rows per block (4 waves x 64 rows)
#define BN    32                  // columns staged per iteration
#define ITERS (CPS / BN)          // 128 phase-B iterations
#define SAMPLE_ITERS 64           // phase A: threshold from first 2048 cols of split
#define TILEB 32768               // one staged tile: 32 cols x 1KB
#define NBUF  3                   // triple buffer, counted-vmcnt pipeline

typedef __attribute__((ext_vector_type(4)))  float f32x4;
typedef __attribute__((ext_vector_type(16))) float f32x16;
typedef __attribute__((ext_vector_type(8)))  short s16x8;

__device__ __forceinline__ unsigned short f2bf(float f) {
    unsigned int x = __float_as_uint(f);
    return (unsigned short)((x + 0x7FFFu + ((x >> 16) & 1u)) >> 16);
}

__device__ __forceinline__ void gload_lds16(const void* g, void* l) {
    __builtin_amdgcn_global_load_lds(
        (const __attribute__((address_space(1))) void*)g,
        (__attribute__((address_space(3))) void*)l, 16, 0, 0);
}
__device__ __forceinline__ void gload_lds4(const void* g, void* l) {
    __builtin_amdgcn_global_load_lds(
        (const __attribute__((address_space(1))) void*)g,
        (__attribute__((address_space(3))) void*)l, 4, 0, 0);
}

// pin an A-fragment into the AGPR file: opaque value -> no remat, no VGPR-class pressure
__device__ __forceinline__ void pinA(s16x8& v) { asm volatile("" : "+a"(v)); }

__device__ __forceinline__ f32x16 zero16() {
    f32x16 z;
    #pragma unroll
    for (int i = 0; i < 16; ++i) z[i] = 0.f;
    return z;
}

// scalar exact top-KSEL (smallest) scan over v[0..n); result in a[KSEL]; returns 11th smallest
__device__ __forceinline__ float topk_scan(const float* v, int n, float* a) {
    #pragma unroll
    for (int p = 0; p < KSEL; ++p) a[p] = v[p];
    float mx = a[0];
    #pragma unroll
    for (int p = 1; p < KSEL; ++p) mx = fmaxf(mx, a[p]);
    for (int i = KSEL; i < n; ++i) {
        const float x = v[i];
        if (x < mx) {
            bool done = false;
            #pragma unroll
            for (int p = 0; p < KSEL; ++p) {
                const bool rep = (!done) && (a[p] == mx);
                a[p] = rep ? x : a[p];
                done = done || rep;
            }
            mx = a[0];
            #pragma unroll
            for (int p = 1; p < KSEL; ++p) mx = fmaxf(mx, a[p]);
        }
    }
    return mx;
}

// ---- kernel 1: fused fp32->bf16 convert into fragment-major layout + ||x_i||^2
//   layout: byte(row,k) = (row>>5)*32768 + (k>>4)*1024 + ((k>>3)&1)*512 + (row&31)*16 + (k&7)*2
//   (this makes 32x32x16-MFMA A-loads, B ds_reads, and global_load_lds staging all lane-linear)
__global__ void prep_convert(const float* __restrict__ obs, char* __restrict__ obsb,
                             float* __restrict__ sq) {
    const int wv = threadIdx.x >> 6, ln = threadIdx.x & 63;
    const int row = blockIdx.x * 4 + wv;
    const float4* s = (const float4*)(obs + (unsigned long)row * DIM + ln * 8);
    const float4 a = s[0], b = s[1];
    uint4 o;
    o.x = (unsigned int)f2bf(a.x) | ((unsigned int)f2bf(a.y) << 16);
    o.y = (unsigned int)f2bf(a.z) | ((unsigned int)f2bf(a.w) << 16);
    o.z = (unsigned int)f2bf(b.x) | ((unsigned int)f2bf(b.y) << 16);
    o.w = (unsigned int)f2bf(b.z) | ((unsigned int)f2bf(b.w) << 16);
    // lane ln owns k in [ln*8, ln*8+8): t = ln>>1, kh = ln&1
    *(uint4*)(obsb + (unsigned long)(row >> 5) * TILEB + (ln >> 1) * 1024
              + (ln & 1) * 512 + (row & 31) * 16) = o;
    float ss = a.x*a.x + a.y*a.y + a.z*a.z + a.w*a.w
             + b.x*b.x + b.y*b.y + b.z*b.z + b.w*b.w;
    #pragma unroll
    for (int off = 32; off; off >>= 1) ss += __shfl_xor(ss, off);
    if (ln == 0) sq[row] = ss;
}

// ---- kernel 2: two-phase fused distance GEMM (32x32x16 MFMA, R=64 rows/wave) + exact top-11
__global__ __launch_bounds__(256, 1) void knn_main(
    const char* __restrict__ obsb, const float* __restrict__ sq,
    float* __restrict__ cand)
{
    __shared__ __align__(16) char Braw[NBUF][TILEB];   // 96 KB triple buffer
    __shared__ float sqs[NBUF][64];
    __shared__ float Trow[BM];

    const int tid = threadIdx.x;
    const int wv = tid >> 6, ln = tid & 63;
    // XCD-bijective swizzle: 256 blocks, 8 XCDs -> each XCD = 32 row-tiles of ONE split
    const int swz = (blockIdx.x & 7) * 32 + (blockIdx.x >> 3);
    const int sp = swz >> 6;                 // split 0..3
    const int rt = swz & 63;                 // row tile 0..63
    const int R0 = rt * BM;
    const int C0 = sp * CPS;
    const int wrow0 = R0 + wv * 64;
    const int lc = ln & 31;                  // row-within-strip (A) / col (B) index
    const int hi = ln >> 5;                  // k-half / col-slot half

    // A fragments: 2 strips x 32 k-steps, loaded once, pinned to AGPRs
    s16x8 afrag[2][32];
    float sqr[2];
    #pragma unroll
    for (int s = 0; s < 2; ++s) {
        const unsigned long sbase = (unsigned long)((wrow0 >> 5) + s) * TILEB;
        #pragma unroll
        for (int t = 0; t < 32; ++t) {
            afrag[s][t] = *(const s16x8*)(obsb + sbase + t * 1024 + ln * 16);
            pinA(afrag[s][t]);
        }
        sqr[s] = sq[wrow0 + s * 32 + lc];
    }
    asm volatile("" : "+v"(sqr[0]), "+v"(sqr[1]));   // retire sqr loads before staging

    // stage tile CIT into buffer NB: 8 x 1KB lane-linear copies + sq tile = 9 vmem/wave
#define STAGE_FULL(NB, CIT) do {                                                \
        const char* gs_ = obsb + (unsigned long)((C0 >> 5) + (CIT)) * TILEB     \
                          + wv * 8192 + ln * 16;                                \
        char* lb_ = &Braw[NB][0] + wv * 8192;                                   \
        _Pragma("unroll")                                                       \
        for (int r_ = 0; r_ < 8; ++r_)                                          \
            gload_lds16(gs_ + r_ * 1024, lb_ + r_ * 1024);                      \
        gload_lds4(sq + C0 + (CIT) * BN + lc, &sqs[NB][0]);                     \
    } while (0)

#define GEMM_CORE()                                                             \
        const char* bp = &Braw[0][0] + bR * TILEB;                              \
        f32x16 acc0 = zero16(), acc1 = zero16();                                \
        _Pragma("unroll")                                                       \
        for (int t = 0; t < 32; ++t) {                                          \
            const s16x8 bf = *(const s16x8*)(bp + t * 1024 + ln * 16);          \
            acc0 = __builtin_amdgcn_mfma_f32_32x32x16_bf16(bf, afrag[0][t], acc0, 0, 0, 0); \
            acc1 = __builtin_amdgcn_mfma_f32_32x32x16_bf16(bf, afrag[1][t], acc1, 0, 0, 0); \
        }                                                                       \
        f32x4 sqv[4];                                                           \
        _Pragma("unroll")                                                       \
        for (int j = 0; j < 4; ++j)                                             \
            sqv[j] = *(const f32x4*)&sqs[bR][j * 8 + hi * 4];

    // C/D 32x32 layout: col(=obs-row) = ln&31; row(=obs-col) = (r&3)+8*(r>>2)+4*hi
#define DISTA(S, R) fmaf(-2.f, acc##S[R], sqr[S] + sqv[(R) >> 2][(R) & 3])

#define BOUNDARY(NIT) do {                                                      \
        if (it < (NIT) - 2) asm volatile("s_waitcnt vmcnt(9)" ::: "memory");    \
        else                asm volatile("s_waitcnt vmcnt(0)" ::: "memory");    \
        __builtin_amdgcn_s_barrier();                                           \
        const int tb_ = bR; bR = bM; bM = bS; bS = tb_;                         \
    } while (0)

    // ================= phase A: slot minima over 2048 sampled cols =================
    float segmin[2][16];
    #pragma unroll
    for (int s = 0; s < 2; ++s)
        #pragma unroll
        for (int r = 0; r < 16; ++r) segmin[s][r] = __builtin_inff();

    int bR = 0, bM = 1, bS = 2;
    STAGE_FULL(0, 0);
    STAGE_FULL(1, 1);
    asm volatile("s_waitcnt vmcnt(9)" ::: "memory");
    __builtin_amdgcn_s_barrier();

    for (int it = 0; it < SAMPLE_ITERS; ++it) {
        if (it + 2 < SAMPLE_ITERS) STAGE_FULL(bS, it + 2);
        GEMM_CORE();
        #pragma unroll
        for (int r = 0; r < 16; ++r) {
            segmin[0][r] = fminf(segmin[0][r], DISTA(0, r));
            segmin[1][r] = fminf(segmin[1][r], DISTA(1, r));
        }
        BOUNDARY(SAMPLE_ITERS);
    }

    // gather 32 slot-minima per row (2 lanes x 16 slots), stride 33 -> T
    // (slot minima are ACTUAL distances at distinct columns => T is a provable
    //  upper bound of the row's true 11th smallest; phase B recomputes all
    //  columns bit-identically, so the gate is exact.)
    float* mins = (float*)&Braw[0][0];               // [BM][33]
    #pragma unroll
    for (int s = 0; s < 2; ++s)
        #pragma unroll
        for (int r = 0; r < 16; ++r)
            mins[(wv * 64 + s * 32 + lc) * 33 + hi * 16 + r] = segmin[s][r];
    __syncthreads();
    {
        float a[KSEL];
        Trow[tid] = topk_scan(mins + tid * 33, 32, a);
    }
    __syncthreads();

    // ================= phase B: seeded per-lane register heaps =================
    float hp[2][KSEL], hmax[2], mxv[2], tseed[2];
    #pragma unroll
    for (int s = 0; s < 2; ++s) {
        #pragma unroll
        for (int p = 0; p < KSEL; ++p) hp[s][p] = __builtin_inff();
        hmax[s]  = __builtin_inff();
        tseed[s] = Trow[wv * 64 + s * 32 + lc] + 1e-3f;
        mxv[s]   = tseed[s];
    }
    __syncthreads();   // Trow/mins reads done before Braw re-staged

#define INS(S, VV) do {                                                         \
        if ((VV) < mxv[S]) {                                                    \
            bool done_ = false;                                                 \
            _Pragma("unroll")                                                   \
            for (int p = 0; p < KSEL; ++p) {                                    \
                const bool rep_ = (!done_) && (hp[S][p] == hmax[S]);            \
                hp[S][p] = rep_ ? (VV) : hp[S][p];                              \
                done_ = done_ || rep_;                                          \
            }                                                                   \
            float m_ = hp[S][0];                                                \
            _Pragma("unroll")                                                   \
            for (int p = 1; p < KSEL; ++p) m_ = fmaxf(m_, hp[S][p]);            \
            hmax[S] = m_;                                                       \
            mxv[S]  = fminf(tseed[S], m_);                                      \
        }                                                                       \
    } while (0)

#define PB_STRIP(S) do {                                                        \
        float dd[16];                                                           \
        _Pragma("unroll")                                                       \
        for (int r = 0; r < 16; ++r) dd[r] = DISTA(S, r);                       \
        float vm = dd[0];                                                       \
        _Pragma("unroll")                                                       \
        for (int r = 1; r < 16; ++r) vm = fminf(vm, dd[r]);                     \
        if (__any(vm < mxv[S])) {                                               \
            _Pragma("unroll")                                                   \
            for (int r = 0; r < 16; ++r) INS(S, dd[r]);                         \
        }                                                                       \
    } while (0)

    bR = 0; bM = 1; bS = 2;
    STAGE_FULL(0, 0);
    STAGE_FULL(1, 1);
    asm volatile("s_waitcnt vmcnt(9)" ::: "memory");
    __builtin_amdgcn_s_barrier();

    for (int it = 0; it < ITERS; ++it) {
        if (it + 2 < ITERS) STAGE_FULL(bS, it + 2);
        GEMM_CORE();
        PB_STRIP(0);
        PB_STRIP(1);
        BOUNDARY(ITERS);
    }

    // merge 2 lanes x 11 per row -> exact top-11 of this split (stride 23)
    float* sc2 = (float*)&Braw[0][0];                // [BM][23]
    #pragma unroll
    for (int s = 0; s < 2; ++s)
        #pragma unroll
        for (int p = 0; p < KSEL; ++p)
            sc2[(wv * 64 + s * 32 + lc) * 23 + hi * KSEL + p] = hp[s][p];
    __syncthreads();
    {
        float a[KSEL];
        topk_scan(sc2 + tid * 23, 2 * KSEL, a);
        #pragma unroll
        for (int p = 0; p < KSEL; ++p)
            cand[(unsigned long)(R0 + tid) * (NSPLIT * KSEL) + sp * KSEL + p] = a[p];
    }
}

// ---- kernel 3: merge 4x11 split candidates per row -> output
__global__ void merge_out(const float* __restrict__ cand, float* __restrict__ out) {
    const int row = blockIdx.x * 256 + threadIdx.x;
    const float* c = cand + (unsigned long)row * (NSPLIT * KSEL);
    float arr[KSEL];
    topk_scan(c, NSPLIT * KSEL, arr);
    float mn = arr[0];
    #pragma unroll
    for (int q = 1; q < KSEL; ++q) mn = fminf(mn, arr[q]);
    float ssum = 0.f;
    #pragma unroll
    for (int q = 0; q < KSEL; ++q) ssum += sqrtf(fmaxf(arr[q], 0.f));
    out[row] = log1pf((ssum - sqrtf(fmaxf(mn, 0.f))) * 0.1f);
}

extern "C" void kernel_launch(void* const* d_in, const int* in_sizes, int n_in,
                              void* d_out, int out_size, void* d_ws, size_t ws_size,
                              hipStream_t stream) {
    const float* obs = (const float*)d_in[0];
    float* out = (float*)d_out;
    char* ws = (char*)d_ws;

    char*  obsb = ws;                                        // 16 MB fragment-major bf16
    float* sq   = (float*)(ws + (size_t)NPTS * 1024);        // 64 KB
    float* cand = (float*)(ws + (size_t)NPTS * 1024 + NPTS * sizeof(float)); // ~2.9 MB

    prep_convert<<<NPTS / 4, 256, 0, stream>>>(obs, obsb, sq);
    knn_main<<<64 * NSPLIT, 256, 0, stream>>>(obsb, sq, cand);   // 256 blocks, 1/CU
    merge_out<<<NPTS / 256, 256, 0, stream>>>(cand, out);
}

// Round 7
// 544.558 us; speedup vs baseline: 1.3343x; 1.3343x over previous
//
#include <hip/hip_runtime.h>
#include <math.h>

// ---- problem constants (fixed shapes) ----
#define NPTS 16384
#define DIM  512
#define KSEL 11                   // K+1 smallest incl. self; min dropped at the end
#define NSPLIT 4
#define CPS   (NPTS / NSPLIT)     // 4096 columns per split
#define BM    128                 // rows per block (4 waves x 32 rows)
#define BN    32                  // columns staged per iteration (32 KB)
#define ITERS (CPS / BN)          // 128 phase-B iterations
#define SAMPLE_ITERS 64           // phase A: threshold from first 2048 cols of split
#define STRIPB 16384              // bytes per 16-row fragment-major strip

typedef __attribute__((ext_vector_type(4))) float f32x4;
typedef __attribute__((ext_vector_type(8))) short s16x8;

__device__ __forceinline__ unsigned short f2bf(float f) {
    unsigned int x = __float_as_uint(f);
    return (unsigned short)((x + 0x7FFFu + ((x >> 16) & 1u)) >> 16);
}

__device__ __forceinline__ void gload_lds16(const void* g, void* l) {
    __builtin_amdgcn_global_load_lds(
        (const __attribute__((address_space(1))) void*)g,
        (__attribute__((address_space(3))) void*)l, 16, 0, 0);
}

// pin a loaded fragment: value becomes opaque -> compiler cannot rematerialize
__device__ __forceinline__ void pinreg(s16x8& v) { asm volatile("" : "+v"(v)); }

// scalar exact top-KSEL (smallest) scan over v[0..n); result in a[KSEL]; returns 11th smallest
__device__ __forceinline__ float topk_scan(const float* v, int n, float* a) {
    #pragma unroll
    for (int p = 0; p < KSEL; ++p) a[p] = v[p];
    float mx = a[0];
    #pragma unroll
    for (int p = 1; p < KSEL; ++p) mx = fmaxf(mx, a[p]);
    for (int i = KSEL; i < n; ++i) {
        const float x = v[i];
        if (x < mx) {
            bool done = false;
            #pragma unroll
            for (int p = 0; p < KSEL; ++p) {
                const bool rep = (!done) && (a[p] == mx);
                a[p] = rep ? x : a[p];
                done = done || rep;
            }
            mx = a[0];
            #pragma unroll
            for (int p = 1; p < KSEL; ++p) mx = fmaxf(mx, a[p]);
        }
    }
    return mx;
}

// ---- kernel 1: fused fp32->bf16 convert into fragment-major layout + ||x_i||^2
//   byte(row,k) = (row>>4)*16384 + (k>>5)*1024 + ((k>>3)&3)*256 + (row&15)*16 + (k&7)*2
//   => MFMA fragment loads (A global, B LDS) and staging are all base + lane*16 (linear).
//   one wave per row: lane ln owns k in [ln*8, ln*8+8): t=ln>>2, kc=ln&3
__global__ void prep_convert(const float* __restrict__ obs, char* __restrict__ obsb,
                             float* __restrict__ sq) {
    const int wv = threadIdx.x >> 6, ln = threadIdx.x & 63;
    const int row = blockIdx.x * 4 + wv;
    const float4* s = (const float4*)(obs + (unsigned long)row * DIM + ln * 8);
    const float4 a = s[0], b = s[1];
    uint4 o;
    o.x = (unsigned int)f2bf(a.x) | ((unsigned int)f2bf(a.y) << 16);
    o.y = (unsigned int)f2bf(a.z) | ((unsigned int)f2bf(a.w) << 16);
    o.z = (unsigned int)f2bf(b.x) | ((unsigned int)f2bf(b.y) << 16);
    o.w = (unsigned int)f2bf(b.z) | ((unsigned int)f2bf(b.w) << 16);
    *(uint4*)(obsb + (unsigned long)(row >> 4) * STRIPB + (ln >> 2) * 1024
              + (ln & 3) * 256 + (row & 15) * 16) = o;
    float ss = a.x*a.x + a.y*a.y + a.z*a.z + a.w*a.w
             + b.x*b.x + b.y*b.y + b.z*b.z + b.w*b.w;
    #pragma unroll
    for (int off = 32; off; off >>= 1) ss += __shfl_xor(ss, off);
    if (ln == 0) sq[row] = ss;
}

// ---- kernel 2: two-phase fused distance GEMM + exact per-row top-11
__global__ __launch_bounds__(256, 2) void knn_main(
    const char* __restrict__ obsb, const float* __restrict__ sq,
    float* __restrict__ cand)
{
    __shared__ __align__(16) char Braw[2][BN * 1024];   // 64 KB double buffer
    __shared__ float Trow[BM];

    const int tid = threadIdx.x;
    const int wv = tid >> 6, ln = tid & 63;
    // XCD-bijective swizzle (512 % 8 == 0): each XCD owns 64 consecutive swz
    // => one split's 4MB column panel per XCD L2.
    const int swz = (blockIdx.x & 7) * 64 + (blockIdx.x >> 3);
    const int sp = swz >> 7;                 // split 0..3
    const int rt = swz & 127;                // row tile 0..127
    const int R0 = rt * BM;
    const int C0 = sp * CPS;
    const int wrow0 = R0 + wv * 32;
    const int lr = ln & 15;                  // fragment free-dim index
    const int kc = ln >> 4;                  // k-chunk 0..3
    const int lfrag = kc * 256 + lr * 16;    // per-lane offset inside a 1KB t-block

    // A fragments (row points): load once, pin in registers for both phases
    s16x8 afrag[2][16];
    float sqr[2];
    #pragma unroll
    for (int s = 0; s < 2; ++s) {
        const unsigned long sbase = (unsigned long)((R0 >> 4) + wv * 2 + s) * STRIPB;
        #pragma unroll
        for (int t = 0; t < 16; ++t) {
            afrag[s][t] = *(const s16x8*)(obsb + sbase + t * 1024 + lfrag);
            pinreg(afrag[s][t]);
        }
        sqr[s] = sq[wrow0 + s * 16 + lr];
    }

#define STAGE(BUF, CITER) do {                                                  \
        const char* gs_ = obsb + (unsigned long)((C0 >> 4) + 2 * (CITER)) * STRIPB \
                          + wv * 8192 + ln * 16;                                \
        char* lb_ = &Braw[BUF][0] + wv * 8192;                                  \
        _Pragma("unroll")                                                       \
        for (int r_ = 0; r_ < 8; ++r_)                                          \
            gload_lds16(gs_ + r_ * 1024, lb_ + r_ * 1024);                      \
    } while (0)

#define GEMM_BODY(CUR, CITER)                                                   \
        const char* bp = &Braw[CUR][0];                                         \
        f32x4 acc[2][2] = {{{0.f,0.f,0.f,0.f},{0.f,0.f,0.f,0.f}},               \
                           {{0.f,0.f,0.f,0.f},{0.f,0.f,0.f,0.f}}};              \
        _Pragma("unroll")                                                       \
        for (int cg = 0; cg < 2; ++cg) {                                        \
            _Pragma("unroll")                                                   \
            for (int t = 0; t < 16; ++t) {                                      \
                const s16x8 b = *(const s16x8*)(bp + cg * STRIPB + t * 1024 + lfrag); \
                acc[0][cg] = __builtin_amdgcn_mfma_f32_16x16x32_bf16(b, afrag[0][t], acc[0][cg], 0, 0, 0); \
                acc[1][cg] = __builtin_amdgcn_mfma_f32_16x16x32_bf16(b, afrag[1][t], acc[1][cg], 0, 0, 0); \
            }                                                                   \
        }                                                                       \
        f32x4 sqv[2];                                                           \
        sqv[0] = *(const f32x4*)(sq + C0 + (CITER) * BN + kc * 4);              \
        sqv[1] = *(const f32x4*)(sq + C0 + (CITER) * BN + 16 + kc * 4);

#define DIST(S, CG, R) fmaf(-2.0f, acc[S][CG][R], sqr[S] + sqv[CG][R])

    // ================= phase A: slot minima over sampled 2048 cols =================
    float segmin[2][8];
    #pragma unroll
    for (int s = 0; s < 2; ++s)
        #pragma unroll
        for (int q = 0; q < 8; ++q) segmin[s][q] = __builtin_inff();

    STAGE(0, 0);
    __syncthreads();
    #pragma unroll 2
    for (int it = 0; it < SAMPLE_ITERS; ++it) {
        const int cur = it & 1;
        if (it + 1 < SAMPLE_ITERS) STAGE(cur ^ 1, it + 1);
        GEMM_BODY(cur, it);
        #pragma unroll
        for (int s = 0; s < 2; ++s)
            #pragma unroll
            for (int cg = 0; cg < 2; ++cg)
                #pragma unroll
                for (int r = 0; r < 4; ++r)
                    segmin[s][cg * 4 + r] = fminf(segmin[s][cg * 4 + r], DIST(s, cg, r));
        __syncthreads();
    }

    // gather 32 slot-minima per row (stride 33 to avoid bank conflicts) -> T
    // (slot minima are ACTUAL distances at distinct columns => T is a provable
    //  upper bound of the row's true 11th smallest; phase B recomputes all
    //  columns bit-identically, so the gate is exact.)
    float* mins = (float*)&Braw[0][0];               // [BM][33]
    #pragma unroll
    for (int s = 0; s < 2; ++s)
        #pragma unroll
        for (int q = 0; q < 8; ++q)
            mins[(wv * 32 + s * 16 + lr) * 33 + kc * 8 + q] = segmin[s][q];
    __syncthreads();
    if (tid < BM) {
        float a[KSEL];
        Trow[tid] = topk_scan(mins + tid * 33, 32, a);
    }
    __syncthreads();

    // ================= phase B: seeded per-lane register heaps =================
    float hp[2][KSEL], hmax[2], mxv[2], tseed[2];
    #pragma unroll
    for (int s = 0; s < 2; ++s) {
        #pragma unroll
        for (int p = 0; p < KSEL; ++p) hp[s][p] = __builtin_inff();
        hmax[s]  = __builtin_inff();
        tseed[s] = Trow[wv * 32 + s * 16 + lr] + 1e-3f;
        mxv[s]   = tseed[s];
    }
    __syncthreads();   // Trow read before Braw[0] re-staged below

#define INS(S, VV) do {                                                         \
        if (__any((VV) < mxv[S])) {                                             \
            const bool ins_ = (VV) < mxv[S];                                    \
            bool done_ = !ins_;                                                 \
            _Pragma("unroll")                                                   \
            for (int p = 0; p < KSEL; ++p) {                                    \
                const bool rep_ = (!done_) && (hp[S][p] == hmax[S]);            \
                hp[S][p] = rep_ ? (VV) : hp[S][p];                              \
                done_ = done_ || rep_;                                          \
            }                                                                   \
            float m_ = hp[S][0];                                                \
            _Pragma("unroll")                                                   \
            for (int p = 1; p < KSEL; ++p) m_ = fmaxf(m_, hp[S][p]);            \
            hmax[S] = m_;                                                       \
            mxv[S]  = fminf(tseed[S], m_);                                      \
        }                                                                       \
    } while (0)

#define PHASEB_STRIP(S) do {                                                    \
        const float w0 = DIST(S,0,0), w1 = DIST(S,0,1), w2 = DIST(S,0,2), w3 = DIST(S,0,3); \
        const float w4 = DIST(S,1,0), w5 = DIST(S,1,1), w6 = DIST(S,1,2), w7 = DIST(S,1,3); \
        INS(S,w0); INS(S,w1); INS(S,w2); INS(S,w3);                             \
        INS(S,w4); INS(S,w5); INS(S,w6); INS(S,w7);                             \
    } while (0)

    STAGE(0, 0);
    __syncthreads();
    #pragma unroll 2
    for (int it = 0; it < ITERS; ++it) {
        const int cur = it & 1;
        if (it + 1 < ITERS) STAGE(cur ^ 1, it + 1);
        GEMM_BODY(cur, it);
        PHASEB_STRIP(0);
        PHASEB_STRIP(1);
        __syncthreads();
    }

    // merge 4 lanes x 11 per row -> exact top-11 of this split (stride 45, pad)
    float* sc2 = (float*)&Braw[0][0];                // [BM][45]
    #pragma unroll
    for (int s = 0; s < 2; ++s)
        #pragma unroll
        for (int p = 0; p < KSEL; ++p)
            sc2[(wv * 32 + s * 16 + lr) * 45 + kc * KSEL + p] = hp[s][p];
    __syncthreads();
    if (tid < BM) {
        float a[KSEL];
        topk_scan(sc2 + tid * 45, 44, a);
        #pragma unroll
        for (int p = 0; p < KSEL; ++p)
            cand[(unsigned long)(R0 + tid) * (NSPLIT * KSEL) + sp * KSEL + p] = a[p];
    }
}

// ---- kernel 3: merge 4x11 split candidates per row -> output
__global__ void merge_out(const float* __restrict__ cand, float* __restrict__ out) {
    const int row = blockIdx.x * 256 + threadIdx.x;
    const float* c = cand + (unsigned long)row * (NSPLIT * KSEL);
    float arr[KSEL];
    topk_scan(c, NSPLIT * KSEL, arr);
    float mn = arr[0];
    #pragma unroll
    for (int q = 1; q < KSEL; ++q) mn = fminf(mn, arr[q]);
    float ssum = 0.f;
    #pragma unroll
    for (int q = 0; q < KSEL; ++q) ssum += sqrtf(fmaxf(arr[q], 0.f));
    out[row] = log1pf((ssum - sqrtf(fmaxf(mn, 0.f))) * 0.1f);
}

extern "C" void kernel_launch(void* const* d_in, const int* in_sizes, int n_in,
                              void* d_out, int out_size, void* d_ws, size_t ws_size,
                              hipStream_t stream) {
    const float* obs = (const float*)d_in[0];
    float* out = (float*)d_out;
    char* ws = (char*)d_ws;

    char*  obsb = ws;                                        // 16 MB fragment-major bf16
    float* sq   = (float*)(ws + (size_t)NPTS * 1024);        // 64 KB
    float* cand = (float*)(ws + (size_t)NPTS * 1024 + NPTS * sizeof(float)); // ~2.9 MB

    prep_convert<<<NPTS / 4, 256, 0, stream>>>(obs, obsb, sq);
    knn_main<<<(NPTS / BM) * NSPLIT, 256, 0, stream>>>(obsb, sq, cand);  // 512 blocks
    merge_out<<<NPTS / 256, 256, 0, stream>>>(cand, out);
}